// Round 2
// baseline (758.070 us; speedup 1.0000x reference)
//
#include <hip/hip_runtime.h>
#include <math.h>

// Problem constants
#define B_ 8
#define T_ 64
#define N_ 197
#define D_ 768
#define HIDD_ 3072   // HID*D
#define KF_ 8
#define KT_ 49
#define GSTRIDE 200  // padded row stride of per-pair Gram matrix (doubles)

// Output layout (floats, concatenated in reference return order)
#define Z_SZ    (B_*KF_*KT_*D_)       // 2408448
#define FI_OFF  (Z_SZ)                // 2408448
#define TI_OFF  (FI_OFF + B_*KF_)     // 2408512
#define FM_OFF  (TI_OFF + B_*KF_*KT_) // 2411648
#define TM_OFF  (FM_OFF + B_*T_)      // 2412160
#define TM_SZ   (B_*T_*N_)            // 100864

// Workspace layout (bytes)
#define WS_SCOREP  0                          // 512*24 doubles = 98304
#define WS_FN64    98304                      // 512*768*8 = 3145728
#define WS_H32     (WS_FN64 + 3145728)        // 512*768*4 = 1572864
#define WS_VALID   (WS_H32 + 1572864)         // 512*4 = 2048
#define WS_FIDX    (WS_VALID + 2048)          // 64 ints (pad 256)
#define WS_SIM     (WS_FIDX + 256)            // 8*64*64*8 = 262144
#define WS_G       (WS_SIM + 262144)          // 64*200*200*8 = 20480000
// total ~25.6 MB

// ---------------------------------------------------------------------------
// Kernel A: masked-mean frame_repr (fp64), LayerNorm -> h32, L2-normalized
// fn64, valid flags. One block per (b,t); threads 0..191 own 4 dims (float4).
// ---------------------------------------------------------------------------
__global__ __launch_bounds__(256) void kA(const float* __restrict__ x,
                                          const float* __restrict__ mask,
                                          const float* __restrict__ gamma,
                                          const float* __restrict__ beta,
                                          double* __restrict__ fn64,
                                          float* __restrict__ h32,
                                          int* __restrict__ validw) {
  const int row = blockIdx.x;          // b*T + t
  const int tid = threadIdx.x;
  __shared__ float  ms[N_];
  __shared__ double red[256];
  __shared__ double sh_denom, sh_mu, sh_sd, sh_nrm;
  const float* xr = x + (size_t)row * (N_ * D_);

  if (tid < N_) ms[tid] = mask[(size_t)row * N_ + tid];
  __syncthreads();

  // denom = clip(sum(mask), 1e-6)
  red[tid] = (tid < N_) ? (double)ms[tid] : 0.0;
  __syncthreads();
  for (int s = 128; s > 0; s >>= 1) { if (tid < s) red[tid] += red[tid + s]; __syncthreads(); }
  if (tid == 0) { double d = red[0]; sh_denom = (d > 1e-6) ? d : 1e-6; }
  __syncthreads();
  const double dn = sh_denom;

  // masked mean over n (fp64 accumulate), float4 vector loads
  double a0 = 0.0, a1 = 0.0, a2 = 0.0, a3 = 0.0;
  if (tid < 192) {
    const float* px = xr + tid * 4;
#pragma unroll 4
    for (int n = 0; n < N_; n++) {
      const double mv = (double)ms[n];
      const float4 v = *(const float4*)(px + (size_t)n * D_);
      a0 += (double)v.x * mv;
      a1 += (double)v.y * mv;
      a2 += (double)v.z * mv;
      a3 += (double)v.w * mv;
    }
  }
  const double f0 = a0 / dn, f1 = a1 / dn, f2 = a2 / dn, f3 = a3 / dn;

  // mean
  red[tid] = (tid < 192) ? (f0 + f1 + f2 + f3) : 0.0; __syncthreads();
  for (int s = 128; s > 0; s >>= 1) { if (tid < s) red[tid] += red[tid + s]; __syncthreads(); }
  if (tid == 0) sh_mu = red[0] / (double)D_;
  __syncthreads();
  const double mu = sh_mu;

  // L2 norm (cosine normalize, eps 1e-12)
  red[tid] = (tid < 192) ? (f0 * f0 + f1 * f1 + f2 * f2 + f3 * f3) : 0.0; __syncthreads();
  for (int s = 128; s > 0; s >>= 1) { if (tid < s) red[tid] += red[tid + s]; __syncthreads(); }
  if (tid == 0) { double nr = sqrt(red[0]); sh_nrm = (nr > 1e-12) ? nr : 1e-12; }
  __syncthreads();

  // variance
  red[tid] = (tid < 192) ? ((f0 - mu) * (f0 - mu) + (f1 - mu) * (f1 - mu) +
                            (f2 - mu) * (f2 - mu) + (f3 - mu) * (f3 - mu)) : 0.0;
  __syncthreads();
  for (int s = 128; s > 0; s >>= 1) { if (tid < s) red[tid] += red[tid + s]; __syncthreads(); }
  if (tid == 0) sh_sd = sqrt(red[0] / (double)D_ + 1e-5);
  __syncthreads();
  const double sd = sh_sd, nrm = sh_nrm;

  if (tid < 192) {
    const size_t base = (size_t)row * D_;
    const float4 g  = ((const float4*)gamma)[tid];
    const float4 be = ((const float4*)beta)[tid];
    float4 hv;
    hv.x = (float)((f0 - mu) / sd * (double)g.x + (double)be.x);
    hv.y = (float)((f1 - mu) / sd * (double)g.y + (double)be.y);
    hv.z = (float)((f2 - mu) / sd * (double)g.z + (double)be.z);
    hv.w = (float)((f3 - mu) / sd * (double)g.w + (double)be.w);
    *(float4*)(h32 + base + tid * 4) = hv;
    double2* fp = (double2*)(fn64 + base + tid * 4);
    fp[0] = make_double2(f0 / nrm, f1 / nrm);
    fp[1] = make_double2(f2 / nrm, f3 / nrm);
  }
  if (tid == 0) validw[row] = 1;  // clip(denom,1e-6) > 0 always
}

// ---------------------------------------------------------------------------
// Kernel SB: fused kS (sim = fn.fn^T, fp64, 32 blocks) and kB (score GEMM,
// 384 blocks). Independent producers for kD; one dispatch lets the small kS
// ride under kB. Shared-LDS union via char buffer.
// ---------------------------------------------------------------------------
__global__ __launch_bounds__(256) void kSB(const double* __restrict__ fn64,
                                           double* __restrict__ simG,
                                           const float* __restrict__ h32,
                                           const float* __restrict__ W1,
                                           const float* __restrict__ b1,
                                           const float* __restrict__ W2,
                                           double* __restrict__ scorep) {
  __shared__ char smem[42496] __attribute__((aligned(16)));
  const int tid = threadIdx.x;

  if (blockIdx.x < 32) {
    // ---- kS: parallel sim = fn.fn^T (fp64), same k-order as before ----
    const int b    = blockIdx.x >> 2;
    const int tile = blockIdx.x & 3;
    const int ty = tid >> 4;          // row within slab (0..15)
    const int tx = tid & 15;          // col group (0..15)
    double* As = (double*)smem;            // [kk][row16+pad] = 64*17 dbl
    double* Bs = (double*)(smem + 8704);   // [kk][col64+pad2] = 64*66 dbl
    double acc[4] = {0.0, 0.0, 0.0, 0.0};

    for (int kc = 0; kc < 12; kc++) {
#pragma unroll
      for (int it = 0; it < 4; it++) {          // A slab: 16x64 dbl
        const int idx = (it << 8) + tid;
        const int row = idx >> 6, kk = idx & 63;
        As[kk * 17 + row] = fn64[((size_t)(b * T_ + tile * 16 + row)) * D_ + kc * 64 + kk];
      }
#pragma unroll
      for (int it = 0; it < 16; it++) {         // B slab: 64x64 dbl
        const int idx = (it << 8) + tid;
        const int row = idx >> 6, kk = idx & 63;
        Bs[kk * 66 + row] = fn64[((size_t)(b * T_ + row)) * D_ + kc * 64 + kk];
      }
      __syncthreads();
#pragma unroll 8
      for (int kk = 0; kk < 64; kk++) {
        const double a = As[kk * 17 + ty];
        const double* bp = Bs + kk * 66 + tx * 4;
        acc[0] += a * bp[0];
        acc[1] += a * bp[1];
        acc[2] += a * bp[2];
        acc[3] += a * bp[3];
      }
      __syncthreads();
    }
    double* o = simG + ((size_t)b * 64 + tile * 16 + ty) * 64 + tx * 4;
    o[0] = acc[0]; o[1] = acc[1]; o[2] = acc[2]; o[3] = acc[3];
  } else {
    // ---- kB: score partials = gelu(h @ W1 + b1) @ W2 per n-block ----
    const int bid2 = blockIdx.x - 32;
    const int nb = bid2 % 24;          // n-block (0..23)
    const int n0 = nb * 128;
    const int m0 = (bid2 / 24) * 32;
    const int tx = tid & 31;   // 32 col-groups of 4
    const int ty = tid >> 5;   // 8 row-groups of 4
    float* As = (float*)smem;            // [k][m], pad 36 -> b128-aligned
    float* Bs = (float*)(smem + 9216);   // [k][n] = 64*128 f32
    float acc[4][4];
#pragma unroll
    for (int r = 0; r < 4; r++)
#pragma unroll
      for (int c = 0; c < 4; c++) acc[r][c] = 0.0f;

    for (int kc = 0; kc < 12; kc++) {
      const int k0 = kc * 64;
#pragma unroll
      for (int it = 0; it < 8; it++) {           // A: 32x64
        int idx = tid + (it << 8);
        int k = idx & 63, m = idx >> 6;
        As[k * 36 + m] = h32[(size_t)(m0 + m) * D_ + k0 + k];
      }
#pragma unroll
      for (int it = 0; it < 8; it++) {           // B: 64x128 float4
        int idx = tid + (it << 8);
        int k = idx >> 5, n4 = idx & 31;
        const float4 v = *(const float4*)(W1 + (size_t)(k0 + k) * HIDD_ + n0 + (n4 << 2));
        *(float4*)(Bs + k * 128 + (n4 << 2)) = v;
      }
      __syncthreads();
#pragma unroll 16
      for (int kk = 0; kk < 64; kk++) {
        float4 av = *(const float4*)(As + kk * 36 + ty * 4);
        float4 bv = *(const float4*)(Bs + kk * 128 + tx * 4);
        const float a[4] = {av.x, av.y, av.z, av.w};
        const float bb[4] = {bv.x, bv.y, bv.z, bv.w};
#pragma unroll
        for (int r = 0; r < 4; r++)
#pragma unroll
          for (int c = 0; c < 4; c++) acc[r][c] += a[r] * bb[c];
      }
      __syncthreads();
    }

    double part[4] = {0.0, 0.0, 0.0, 0.0};
#pragma unroll
    for (int r = 0; r < 4; r++) {
#pragma unroll
      for (int c = 0; c < 4; c++) {
        const int gn = n0 + tx * 4 + c;
        const double v = (double)(acc[r][c] + b1[gn]);
        const double g = 0.5 * v * (1.0 + erf(v * 0.7071067811865475244));
        part[r] += g * (double)W2[gn];
      }
    }
#pragma unroll
    for (int r = 0; r < 4; r++) {
      double s = part[r];
#pragma unroll
      for (int off = 16; off > 0; off >>= 1) s += __shfl_down(s, off, 32);
      if (tx == 0) scorep[(size_t)(m0 + ty * 4 + r) * 24 + nb] = s;
    }
  }
}

// ---------------------------------------------------------------------------
// Kernel D: facility-location greedy, barrier-free wave-synchronous (wave 0
// runs 8 steps with shfl-only state after a single LDS sim load/barrier).
// ---------------------------------------------------------------------------
__global__ __launch_bounds__(256) void kD(const double* __restrict__ simG,
                                          const double* __restrict__ scorep,
                                          const float* __restrict__ b2,
                                          int* __restrict__ fidxw,
                                          float* __restrict__ out_fidx,
                                          float* __restrict__ out_fmask) {
  const int b = blockIdx.x;
  const int tid = threadIdx.x;
  __shared__ double sim[64 * 64];

  const double2* sp = (const double2*)(simG + (size_t)b * 4096);
#pragma unroll
  for (int it = 0; it < 8; it++) {
    const int idx = (it << 8) + tid;
    ((double2*)sim)[idx] = sp[idx];
  }
  __syncthreads();

  if (tid < 64) {
    // per-lane score (same 24-term summation order as before)
    double s = 0.0;
    const double* pp = scorep + (size_t)(b * T_ + tid) * 24;
    for (int q = 0; q < 24; q++) s += pp[q];
    const double half_score = 0.5 * (s + (double)b2[0]);  // valid always true

    double bc_r = 0.0;
    int chosen_r = 0;

    for (int step = 0; step < KF_; step++) {
      // coverage gain for candidate tid (same ascending-ii fp64 add order)
      double gsum = 0.0;
      for (int ii = 0; ii < 64; ii++) {
        const double bcv = __shfl(bc_r, ii, 64);
        gsum += fmax(bcv, sim[ii * 64 + tid]);
      }
      double tot = gsum + half_score;
      if (chosen_r) tot = -INFINITY;

      // wave argmax, first-max (min index) tie-break == jnp.argmax
      double bv = tot; int bi = tid;
#pragma unroll
      for (int off = 1; off < 64; off <<= 1) {
        const double ov = __shfl_xor(bv, off, 64);
        const int    oi = __shfl_xor(bi, off, 64);
        if (ov > bv || (ov == bv && oi < bi)) { bv = ov; bi = oi; }
      }
      bc_r = fmax(bc_r, sim[bi * 64 + tid]);   // symmetric: == sim[tid][bi]
      if (tid == bi) chosen_r = 1;
      if (tid == 0) {
        fidxw[b * KF_ + step] = bi;
        out_fidx[b * KF_ + step] = (float)bi;
      }
    }
    out_fmask[b * T_ + tid] = chosen_r ? 1.0f : 0.0f;
  }
}

// ---------------------------------------------------------------------------
// Kernel G v2: per-pair Gram G[i][j] = dot(X_i, X_j), fp64 accumulate.
// Changes vs v1 (all bit-exact: per-output FMA order over k unchanged):
//  * fp64 LDS staging — cvt once at stage (16/kc/thread) instead of 256 in
//    the inner loop; frees the VALU pipe for v_fma_f64 (was co-saturated).
//  * B micro-column mapping c*16+tx -> 4x ds_read_b64 across 16 distinct
//    banks (conflict-free) instead of 4-way-conflicted b128.
//  * pad 70 dbl: A double4 reads stay 16B-aligned; staging-write conflicts
//    drop 8-way -> 4-way.
//  * diagonal tiles (ti==tj) reuse the A slab for B (no B stage/load).
//  * XCD remap: all 10 tiles of a pair share bid%8 -> same XCD L2 for the
//    605 KB frame re-read; kE2 block p (bid%8==p%8) then reads L2-hot G.
// Grid = 640 (bijective remap, 640%8==0).
// ---------------------------------------------------------------------------
__global__ __launch_bounds__(256) void kG(const float* __restrict__ x,
                                          const int* __restrict__ fidxw,
                                          double* __restrict__ G) {
  static const int TIa[10] = {0,0,0,0,1,1,1,2,2,3};
  static const int TJa[10] = {0,1,2,3,1,2,3,2,3,3};
  const int bid  = blockIdx.x;
  const int xcd  = bid & 7;
  const int slot = bid >> 3;            // 0..79
  const int p    = xcd + 8 * (slot / 10);
  const int t    = slot % 10;
  const int ti = TIa[t], tj = TJa[t];
  const int b  = p >> 3;
  const int fi = fidxw[p];
  const float* X = x + ((size_t)(b * T_ + fi)) * (N_ * D_);
  double* Gp = G + (size_t)p * (GSTRIDE * GSTRIDE);

  __shared__ double As[32 * 70];   // [kk][row64+pad6], fp64
  __shared__ double Bs[32 * 70];
  const int tid = threadIdx.x;
  const int tx = tid & 15;         // col lane (cols c*16+tx)
  const int ty = tid >> 4;         // row group (x4 consecutive)
  const bool diag = (ti == tj);
  const double* Bsel = diag ? As : Bs;
  double acc[4][4];
#pragma unroll
  for (int r = 0; r < 4; r++)
#pragma unroll
    for (int c = 0; c < 4; c++) acc[r][c] = 0.0;

  for (int kc = 0; kc < 24; kc++) {
#pragma unroll
    for (int it = 0; it < 2; it++) {
      const int idx = (it << 8) + tid;      // 0..511
      const int row = idx >> 3;             // 0..63
      const int kg  = idx & 7;              // float4 group within 32-k chunk
      const int gra = ti * 64 + row;
      const int ra = (gra < N_) ? gra : (N_ - 1);
      const float4 va = *(const float4*)(X + (size_t)ra * D_ + kc * 32 + kg * 4);
      As[(kg * 4 + 0) * 70 + row] = (double)va.x;
      As[(kg * 4 + 1) * 70 + row] = (double)va.y;
      As[(kg * 4 + 2) * 70 + row] = (double)va.z;
      As[(kg * 4 + 3) * 70 + row] = (double)va.w;
      if (!diag) {
        const int grb = tj * 64 + row;
        const int rb = (grb < N_) ? grb : (N_ - 1);
        const float4 vb = *(const float4*)(X + (size_t)rb * D_ + kc * 32 + kg * 4);
        Bs[(kg * 4 + 0) * 70 + row] = (double)vb.x;
        Bs[(kg * 4 + 1) * 70 + row] = (double)vb.y;
        Bs[(kg * 4 + 2) * 70 + row] = (double)vb.z;
        Bs[(kg * 4 + 3) * 70 + row] = (double)vb.w;
      }
    }
    __syncthreads();
#pragma unroll 8
    for (int kk = 0; kk < 32; kk++) {
      const double* ap = As + kk * 70 + ty * 4;
      const double a0 = ap[0], a1 = ap[1], a2 = ap[2], a3 = ap[3];
      const double* bp = Bsel + kk * 70 + tx;
      const double b0 = bp[0], b1 = bp[16], b2 = bp[32], b3 = bp[48];
      acc[0][0] += a0 * b0; acc[0][1] += a0 * b1; acc[0][2] += a0 * b2; acc[0][3] += a0 * b3;
      acc[1][0] += a1 * b0; acc[1][1] += a1 * b1; acc[1][2] += a1 * b2; acc[1][3] += a1 * b3;
      acc[2][0] += a2 * b0; acc[2][1] += a2 * b1; acc[2][2] += a2 * b2; acc[2][3] += a2 * b3;
      acc[3][0] += a3 * b0; acc[3][1] += a3 * b1; acc[3][2] += a3 * b2; acc[3][3] += a3 * b3;
    }
    __syncthreads();
  }

#pragma unroll
  for (int r = 0; r < 4; r++) {
    const int gi = ti * 64 + ty * 4 + r;
#pragma unroll
    for (int c = 0; c < 4; c++) {
      const int gj = tj * 64 + c * 16 + tx;
      if (gi < N_ && gj < N_) {
        Gp[(size_t)gi * GSTRIDE + gj] = acc[r][c];
        if (!diag) Gp[(size_t)gj * GSTRIDE + gi] = acc[r][c];
      }
    }
  }
}

// ---------------------------------------------------------------------------
// Kernel E2: sequential FPS using precomputed Gram, barrier-free. Wave 0
// owns all candidate slots (4/lane). v2: gdc (diag of cand) comes from the
// owning lane's register via shfl instead of a dependent global load on the
// 48-step serial critical path.
// ---------------------------------------------------------------------------
__global__ __launch_bounds__(256) void kE2(const double* __restrict__ G,
                                           const float* __restrict__ mask,
                                           const int* __restrict__ fidxw,
                                           const float* __restrict__ x,
                                           float* __restrict__ out) {
  const int p = blockIdx.x;
  const int b = p >> 3;
  const int fi = fidxw[p];
  const double* Gp = G + (size_t)p * (GSTRIDE * GSTRIDE);
  const float* mrow = mask + (size_t)(b * T_ + fi) * N_;
  const float* X = x + ((size_t)(b * T_ + fi)) * (N_ * D_);
  const int tid = threadIdx.x;

  __shared__ int toksS[KT_];

  if (tid < 64) {
    const int l = tid;
    double gd[4]; int vld[4]; double md[4];
#pragma unroll
    for (int q = 0; q < 4; q++) {
      const int pt = l + 64 * q;
      const bool live = pt < N_;
      gd[q] = live ? Gp[(size_t)pt * GSTRIDE + pt] : 0.0;
      vld[q] = (live && (mrow[live ? pt : 0] > 0.5f)) ? 1 : 0;
      md[q] = -INFINITY;
    }

    // step 0: argmax over valid of diag (== argmax of where(valid,|X|^2,-inf))
    double bv = vld[0] ? gd[0] : -INFINITY;
    int bi = l;
#pragma unroll
    for (int q = 1; q < 4; q++) {
      const double v = vld[q] ? gd[q] : -INFINITY;
      if (v > bv) { bv = v; bi = l + 64 * q; }   // ascending pt: ties keep min
    }
#pragma unroll
    for (int off = 1; off < 64; off <<= 1) {
      const double ov = __shfl_xor(bv, off, 64);
      const int    oi = __shfl_xor(bi, off, 64);
      if (ov > bv || (ov == bv && oi < bi)) { bv = ov; bi = oi; }
    }
    int cand = bi;
    if (l == 0) toksS[0] = cand;

    for (int k = 1; k < KT_; k++) {
      const size_t rowbase = (size_t)cand * GSTRIDE;
      const double g0 = Gp[rowbase + l];
      const double g1 = Gp[rowbase + l + 64];
      const double g2 = Gp[rowbase + l + 128];
      // diag of cand from the owning lane's register (no dependent L2 load)
      const int cq = cand >> 6, cl = cand & 63;
      const double gsel = (cq == 0) ? gd[0] : (cq == 1) ? gd[1]
                        : (cq == 2) ? gd[2] : gd[3];
      const double gdc = __shfl(gsel, cl, 64);
      const double d0 = sqrt(fmax(gd[0] + gdc - 2.0 * g0, 0.0));
      const double d1 = sqrt(fmax(gd[1] + gdc - 2.0 * g1, 0.0));
      const double d2 = sqrt(fmax(gd[2] + gdc - 2.0 * g2, 0.0));
      md[0] = vld[0] ? ((k == 1) ? d0 : fmin(md[0], d0)) : -1.0;
      md[1] = vld[1] ? ((k == 1) ? d1 : fmin(md[1], d1)) : -1.0;
      md[2] = vld[2] ? ((k == 1) ? d2 : fmin(md[2], d2)) : -1.0;
      if (l + 192 < N_) {
        const double g3 = Gp[rowbase + l + 192];
        const double d3 = sqrt(fmax(gd[3] + gdc - 2.0 * g3, 0.0));
        md[3] = vld[3] ? ((k == 1) ? d3 : fmin(md[3], d3)) : -1.0;
      }

      bv = md[0]; bi = l;
      if (md[1] > bv) { bv = md[1]; bi = l + 64; }
      if (md[2] > bv) { bv = md[2]; bi = l + 128; }
      if (md[3] > bv) { bv = md[3]; bi = l + 192; }
#pragma unroll
      for (int off = 1; off < 64; off <<= 1) {
        const double ov = __shfl_xor(bv, off, 64);
        const int    oi = __shfl_xor(bi, off, 64);
        if (ov > bv || (ov == bv && oi < bi)) { bv = ov; bi = oi; }
      }
      cand = bi;
      if (l == 0) toksS[k] = cand;
    }
  }
  __syncthreads();

  // fused epilogue: token_idx, token_mask, z gather
  if (tid < KT_) {
    const int tok = toksS[tid];
    out[TI_OFF + p * KT_ + tid] = (float)tok;
    out[TM_OFF + (size_t)(b * T_ + fi) * N_ + tok] = 1.0f;
  }
  if (tid < 192) {
    for (int r = 0; r < KT_; r++) {
      const float4 v = *(const float4*)(X + (size_t)toksS[r] * D_ + tid * 4);
      *(float4*)(out + ((size_t)(p * KT_ + r)) * D_ + tid * 4) = v;
    }
  }
}

// ---------------------------------------------------------------------------
extern "C" void kernel_launch(void* const* d_in, const int* in_sizes, int n_in,
                              void* d_out, int out_size, void* d_ws, size_t ws_size,
                              hipStream_t stream) {
  (void)in_sizes; (void)n_in; (void)ws_size; (void)out_size;
  const float* x     = (const float*)d_in[0];
  const float* mask  = (const float*)d_in[1];
  const float* gamma = (const float*)d_in[2];
  const float* beta  = (const float*)d_in[3];
  const float* W1    = (const float*)d_in[4];
  const float* b1    = (const float*)d_in[5];
  const float* W2    = (const float*)d_in[6];
  const float* b2    = (const float*)d_in[7];
  float* out = (float*)d_out;
  char* ws = (char*)d_ws;

  double* scorep = (double*)(ws + WS_SCOREP);
  double* fn64   = (double*)(ws + WS_FN64);
  float*  h32    = (float*)(ws + WS_H32);
  int*    validw = (int*)(ws + WS_VALID);
  int*    fidxw  = (int*)(ws + WS_FIDX);
  double* simG   = (double*)(ws + WS_SIM);
  double* G      = (double*)(ws + WS_G);

  // zero only the token_mask region (everything else is fully overwritten)
  hipMemsetAsync(out + TM_OFF, 0, (size_t)TM_SZ * sizeof(float), stream);

  kA<<<B_ * T_, 256, 0, stream>>>(x, mask, gamma, beta, fn64, h32, validw);
  kSB<<<32 + (HIDD_ / 128) * ((B_ * T_) / 32), 256, 0, stream>>>(
      fn64, simG, h32, W1, b1, W2, scorep);
  kD<<<B_, 256, 0, stream>>>(simG, scorep, b2, fidxw, out + FI_OFF, out + FM_OFF);
  kG<<<B_ * KF_ * 10, 256, 0, stream>>>(x, fidxw, G);
  kE2<<<B_ * KF_, 256, 0, stream>>>(G, mask, fidxw, x, out);
}

// Round 4
// 706.528 us; speedup vs baseline: 1.0730x; 1.0730x over previous
//
#include <hip/hip_runtime.h>
#include <math.h>

// Problem constants
#define B_ 8
#define T_ 64
#define N_ 197
#define D_ 768
#define HIDD_ 3072   // HID*D
#define KF_ 8
#define KT_ 49
#define GSTRIDE 200  // padded row stride of per-pair Gram matrix (doubles)

typedef double dbl4 __attribute__((ext_vector_type(4)));

// Output layout (floats, concatenated in reference return order)
#define Z_SZ    (B_*KF_*KT_*D_)       // 2408448
#define FI_OFF  (Z_SZ)                // 2408448
#define TI_OFF  (FI_OFF + B_*KF_)     // 2408512
#define FM_OFF  (TI_OFF + B_*KF_*KT_) // 2411648
#define TM_OFF  (FM_OFF + B_*T_)      // 2412160
#define TM_SZ   (B_*T_*N_)            // 100864

// Workspace layout (bytes)
#define WS_SCOREP  0                          // 512*24 doubles = 98304
#define WS_FN64    98304                      // 512*768*8 = 3145728
#define WS_H32     (WS_FN64 + 3145728)        // 512*768*4 = 1572864
#define WS_VALID   (WS_H32 + 1572864)         // 512*4 = 2048
#define WS_FIDX    (WS_VALID + 2048)          // 64 ints (pad 256)
#define WS_SIM     (WS_FIDX + 256)            // 8*64*64*8 = 262144
#define WS_G       (WS_SIM + 262144)          // 64*200*200*8 = 20480000
// total ~25.6 MB

// ---------------------------------------------------------------------------
// Kernel A v2: masked-mean frame_repr (fp64), LayerNorm -> h32, L2-normalized
// fn64. One block per (b,t). v2: all 256 threads own 3 dims (256*3 = 768) so
// all 4 waves issue loads (was 192 threads x 4 dims, wave 3 idle) — kernel is
// latency-bound at 2 blocks/CU, +33% outstanding loads. Per-dim masked sums
// keep the exact same per-accumulator fp64 order; only the LDS tree
// reductions reassociate (1e-16 noise; all outputs are gathers/indices with
// >=1e-7 selection margins, established R1/R2).
// ---------------------------------------------------------------------------
__global__ __launch_bounds__(256) void kA(const float* __restrict__ x,
                                          const float* __restrict__ mask,
                                          const float* __restrict__ gamma,
                                          const float* __restrict__ beta,
                                          double* __restrict__ fn64,
                                          float* __restrict__ h32,
                                          int* __restrict__ validw) {
  const int row = blockIdx.x;          // b*T + t
  const int tid = threadIdx.x;
  __shared__ float  ms[N_];
  __shared__ double red[256];
  __shared__ double sh_denom, sh_mu, sh_sd, sh_nrm;
  const float* xr = x + (size_t)row * (N_ * D_);

  if (tid < N_) ms[tid] = mask[(size_t)row * N_ + tid];
  __syncthreads();

  // denom = clip(sum(mask), 1e-6)  (same 197-entry tree as before)
  red[tid] = (tid < N_) ? (double)ms[tid] : 0.0;
  __syncthreads();
  for (int s = 128; s > 0; s >>= 1) { if (tid < s) red[tid] += red[tid + s]; __syncthreads(); }
  if (tid == 0) { double d = red[0]; sh_denom = (d > 1e-6) ? d : 1e-6; }
  __syncthreads();
  const double dn = sh_denom;

  // masked mean over n (fp64 accumulate); 3 consecutive floats per thread
  double a0 = 0.0, a1 = 0.0, a2 = 0.0;
  {
    const float* px = xr + tid * 3;
#pragma unroll 4
    for (int n = 0; n < N_; n++) {
      const double mv = (double)ms[n];
      const float* q = px + (size_t)n * D_;
      a0 += (double)q[0] * mv;
      a1 += (double)q[1] * mv;
      a2 += (double)q[2] * mv;
    }
  }
  const double f0 = a0 / dn, f1 = a1 / dn, f2 = a2 / dn;

  // mean
  red[tid] = f0 + f1 + f2; __syncthreads();
  for (int s = 128; s > 0; s >>= 1) { if (tid < s) red[tid] += red[tid + s]; __syncthreads(); }
  if (tid == 0) sh_mu = red[0] / (double)D_;
  __syncthreads();
  const double mu = sh_mu;

  // L2 norm (cosine normalize, eps 1e-12)
  red[tid] = f0 * f0 + f1 * f1 + f2 * f2; __syncthreads();
  for (int s = 128; s > 0; s >>= 1) { if (tid < s) red[tid] += red[tid + s]; __syncthreads(); }
  if (tid == 0) { double nr = sqrt(red[0]); sh_nrm = (nr > 1e-12) ? nr : 1e-12; }
  __syncthreads();

  // variance
  red[tid] = (f0 - mu) * (f0 - mu) + (f1 - mu) * (f1 - mu) + (f2 - mu) * (f2 - mu);
  __syncthreads();
  for (int s = 128; s > 0; s >>= 1) { if (tid < s) red[tid] += red[tid + s]; __syncthreads(); }
  if (tid == 0) sh_sd = sqrt(red[0] / (double)D_ + 1e-5);
  __syncthreads();
  const double sd = sh_sd, nrm = sh_nrm;

  {
    const size_t base = (size_t)row * D_ + tid * 3;
    const float g0 = gamma[tid * 3 + 0], g1 = gamma[tid * 3 + 1], g2 = gamma[tid * 3 + 2];
    const float e0 = beta[tid * 3 + 0],  e1 = beta[tid * 3 + 1],  e2 = beta[tid * 3 + 2];
    h32[base + 0] = (float)((f0 - mu) / sd * (double)g0 + (double)e0);
    h32[base + 1] = (float)((f1 - mu) / sd * (double)g1 + (double)e1);
    h32[base + 2] = (float)((f2 - mu) / sd * (double)g2 + (double)e2);
    fn64[base + 0] = f0 / nrm;
    fn64[base + 1] = f1 / nrm;
    fn64[base + 2] = f2 / nrm;
  }
  if (tid == 0) validw[row] = 1;  // clip(denom,1e-6) > 0 always
}

// ---------------------------------------------------------------------------
// Kernel SB: fused kS (sim = fn.fn^T, fp64, 32 blocks) and kB (score GEMM,
// 384 blocks). Independent producers for kD; one dispatch lets the small kS
// ride under kB. Shared-LDS union via char buffer.
// ---------------------------------------------------------------------------
__global__ __launch_bounds__(256) void kSB(const double* __restrict__ fn64,
                                           double* __restrict__ simG,
                                           const float* __restrict__ h32,
                                           const float* __restrict__ W1,
                                           const float* __restrict__ b1,
                                           const float* __restrict__ W2,
                                           double* __restrict__ scorep) {
  __shared__ char smem[42496] __attribute__((aligned(16)));
  const int tid = threadIdx.x;

  if (blockIdx.x < 32) {
    // ---- kS: parallel sim = fn.fn^T (fp64), same k-order as before ----
    const int b    = blockIdx.x >> 2;
    const int tile = blockIdx.x & 3;
    const int ty = tid >> 4;          // row within slab (0..15)
    const int tx = tid & 15;          // col group (0..15)
    double* As = (double*)smem;            // [kk][row16+pad] = 64*17 dbl
    double* Bs = (double*)(smem + 8704);   // [kk][col64+pad2] = 64*66 dbl
    double acc[4] = {0.0, 0.0, 0.0, 0.0};

    for (int kc = 0; kc < 12; kc++) {
#pragma unroll
      for (int it = 0; it < 4; it++) {          // A slab: 16x64 dbl
        const int idx = (it << 8) + tid;
        const int row = idx >> 6, kk = idx & 63;
        As[kk * 17 + row] = fn64[((size_t)(b * T_ + tile * 16 + row)) * D_ + kc * 64 + kk];
      }
#pragma unroll
      for (int it = 0; it < 16; it++) {         // B slab: 64x64 dbl
        const int idx = (it << 8) + tid;
        const int row = idx >> 6, kk = idx & 63;
        Bs[kk * 66 + row] = fn64[((size_t)(b * T_ + row)) * D_ + kc * 64 + kk];
      }
      __syncthreads();
#pragma unroll 8
      for (int kk = 0; kk < 64; kk++) {
        const double a = As[kk * 17 + ty];
        const double* bp = Bs + kk * 66 + tx * 4;
        acc[0] += a * bp[0];
        acc[1] += a * bp[1];
        acc[2] += a * bp[2];
        acc[3] += a * bp[3];
      }
      __syncthreads();
    }
    double* o = simG + ((size_t)b * 64 + tile * 16 + ty) * 64 + tx * 4;
    o[0] = acc[0]; o[1] = acc[1]; o[2] = acc[2]; o[3] = acc[3];
  } else {
    // ---- kB: score partials = gelu(h @ W1 + b1) @ W2 per n-block ----
    const int bid2 = blockIdx.x - 32;
    const int nb = bid2 % 24;          // n-block (0..23)
    const int n0 = nb * 128;
    const int m0 = (bid2 / 24) * 32;
    const int tx = tid & 31;   // 32 col-groups of 4
    const int ty = tid >> 5;   // 8 row-groups of 4
    float* As = (float*)smem;            // [k][m], pad 36 -> b128-aligned
    float* Bs = (float*)(smem + 9216);   // [k][n] = 64*128 f32
    float acc[4][4];
#pragma unroll
    for (int r = 0; r < 4; r++)
#pragma unroll
      for (int c = 0; c < 4; c++) acc[r][c] = 0.0f;

    for (int kc = 0; kc < 12; kc++) {
      const int k0 = kc * 64;
#pragma unroll
      for (int it = 0; it < 8; it++) {           // A: 32x64
        int idx = tid + (it << 8);
        int k = idx & 63, m = idx >> 6;
        As[k * 36 + m] = h32[(size_t)(m0 + m) * D_ + k0 + k];
      }
#pragma unroll
      for (int it = 0; it < 8; it++) {           // B: 64x128 float4
        int idx = tid + (it << 8);
        int k = idx >> 5, n4 = idx & 31;
        const float4 v = *(const float4*)(W1 + (size_t)(k0 + k) * HIDD_ + n0 + (n4 << 2));
        *(float4*)(Bs + k * 128 + (n4 << 2)) = v;
      }
      __syncthreads();
#pragma unroll 16
      for (int kk = 0; kk < 64; kk++) {
        float4 av = *(const float4*)(As + kk * 36 + ty * 4);
        float4 bv = *(const float4*)(Bs + kk * 128 + tx * 4);
        const float a[4] = {av.x, av.y, av.z, av.w};
        const float bb[4] = {bv.x, bv.y, bv.z, bv.w};
#pragma unroll
        for (int r = 0; r < 4; r++)
#pragma unroll
          for (int c = 0; c < 4; c++) acc[r][c] += a[r] * bb[c];
      }
      __syncthreads();
    }

    double part[4] = {0.0, 0.0, 0.0, 0.0};
#pragma unroll
    for (int r = 0; r < 4; r++) {
#pragma unroll
      for (int c = 0; c < 4; c++) {
        const int gn = n0 + tx * 4 + c;
        const double v = (double)(acc[r][c] + b1[gn]);
        const double g = 0.5 * v * (1.0 + erf(v * 0.7071067811865475244));
        part[r] += g * (double)W2[gn];
      }
    }
#pragma unroll
    for (int r = 0; r < 4; r++) {
      double s = part[r];
#pragma unroll
      for (int off = 16; off > 0; off >>= 1) s += __shfl_down(s, off, 32);
      if (tx == 0) scorep[(size_t)(m0 + ty * 4 + r) * 24 + nb] = s;
    }
  }
}

// ---------------------------------------------------------------------------
// Kernel D: facility-location greedy, barrier-free wave-synchronous (wave 0
// runs 8 steps with shfl-only state after a single LDS sim load/barrier).
// ---------------------------------------------------------------------------
__global__ __launch_bounds__(256) void kD(const double* __restrict__ simG,
                                          const double* __restrict__ scorep,
                                          const float* __restrict__ b2,
                                          int* __restrict__ fidxw,
                                          float* __restrict__ out_fidx,
                                          float* __restrict__ out_fmask) {
  const int b = blockIdx.x;
  const int tid = threadIdx.x;
  __shared__ double sim[64 * 64];

  const double2* sp = (const double2*)(simG + (size_t)b * 4096);
#pragma unroll
  for (int it = 0; it < 8; it++) {
    const int idx = (it << 8) + tid;
    ((double2*)sim)[idx] = sp[idx];
  }
  __syncthreads();

  if (tid < 64) {
    // per-lane score (same 24-term summation order as before)
    double s = 0.0;
    const double* pp = scorep + (size_t)(b * T_ + tid) * 24;
    for (int q = 0; q < 24; q++) s += pp[q];
    const double half_score = 0.5 * (s + (double)b2[0]);  // valid always true

    double bc_r = 0.0;
    int chosen_r = 0;

    for (int step = 0; step < KF_; step++) {
      // coverage gain for candidate tid (same ascending-ii fp64 add order)
      double gsum = 0.0;
      for (int ii = 0; ii < 64; ii++) {
        const double bcv = __shfl(bc_r, ii, 64);
        gsum += fmax(bcv, sim[ii * 64 + tid]);
      }
      double tot = gsum + half_score;
      if (chosen_r) tot = -INFINITY;

      // wave argmax, first-max (min index) tie-break == jnp.argmax
      double bv = tot; int bi = tid;
#pragma unroll
      for (int off = 1; off < 64; off <<= 1) {
        const double ov = __shfl_xor(bv, off, 64);
        const int    oi = __shfl_xor(bi, off, 64);
        if (ov > bv || (ov == bv && oi < bi)) { bv = ov; bi = oi; }
      }
      bc_r = fmax(bc_r, sim[bi * 64 + tid]);   // symmetric: == sim[tid][bi]
      if (tid == bi) chosen_r = 1;
      if (tid == 0) {
        fidxw[b * KF_ + step] = bi;
        out_fidx[b * KF_ + step] = (float)bi;
      }
    }
    out_fmask[b * T_ + tid] = chosen_r ? 1.0f : 0.0f;
  }
}

// ---------------------------------------------------------------------------
// Kernel G v4: per-pair Gram via v_mfma_f64_16x16x4_f64 with SELF-CALIBRATED
// output layout. v3 failed with the textbook D map (j=lane&15,
// i=4*(lane>>4)+reg); since any transpose-type error is value-identical for
// a Gram (symmetric, same fp64 contraction order), the failure must be a
// non-transpose D permutation (e.g. row interleave i=(lane>>4)+4*reg).
// Fix: two probe mfmas recover each (lane,reg)'s true (i,j) exactly:
//   p1 = mfma(A=lane&15, B=1)  -> D(m,e) = sum_k i = 4*i_true
//   p2 = mfma(A=1, B=lane&15)  -> D(m,e) = sum_k j = 4*j_true
// (b=1 across all lanes makes B=ones under ANY B map; small ints exact.)
// Epilogue scatters with iofs/jofs — correct under any fixed D permutation,
// assuming only the standard A/B input maps (lane = 16*k + {i,j}).
// LDS fp32 [row][k] stride 36; same 640-block symmetric tiling + XCD remap.
// ---------------------------------------------------------------------------
__global__ __launch_bounds__(256) void kG(const float* __restrict__ x,
                                          const int* __restrict__ fidxw,
                                          double* __restrict__ G) {
  static const int TIa[10] = {0,0,0,0,1,1,1,2,2,3};
  static const int TJa[10] = {0,1,2,3,1,2,3,2,3,3};
  const int bid  = blockIdx.x;
  const int xcd  = bid & 7;
  const int slot = bid >> 3;            // 0..79
  const int p    = xcd + 8 * (slot / 10);
  const int t    = slot % 10;
  const int ti = TIa[t], tj = TJa[t];
  const int b  = p >> 3;
  const int fi = fidxw[p];
  const float* X = x + ((size_t)(b * T_ + fi)) * (N_ * D_);
  double* Gp = G + (size_t)p * (GSTRIDE * GSTRIDE);

  __shared__ float As[64 * 36];   // [row][k] fp32, stride 36 (144B, 16B-aligned)
  __shared__ float Bs[64 * 36];
  const int tid  = threadIdx.x;
  const int w    = tid >> 6;      // wave id -> row strip w*16
  const int lane = tid & 63;
  const int lr   = lane & 15;     // A row-in-strip / B col-in-tile
  const int lk   = lane >> 4;     // k slot 0..3
  const bool diag = (ti == tj);
  const float* Bsel = diag ? As : Bs;

  // ---- D-layout probe (exact small-int arithmetic) ----
  dbl4 pz = {0.0, 0.0, 0.0, 0.0};
  const dbl4 p1 = __builtin_amdgcn_mfma_f64_16x16x4f64((double)lr, 1.0, pz, 0, 0, 0);
  const dbl4 p2 = __builtin_amdgcn_mfma_f64_16x16x4f64(1.0, (double)lr, pz, 0, 0, 0);
  int iofs[4], jofs[4];
#pragma unroll
  for (int e = 0; e < 4; e++) {
    iofs[e] = (int)(p1[e] * 0.25 + 0.5);   // true row of (lane, reg e)
    jofs[e] = (int)(p2[e] * 0.25 + 0.5);   // true col of (lane, reg e)
  }

  dbl4 acc0 = {0.0, 0.0, 0.0, 0.0};
  dbl4 acc1 = {0.0, 0.0, 0.0, 0.0};
  dbl4 acc2 = {0.0, 0.0, 0.0, 0.0};
  dbl4 acc3 = {0.0, 0.0, 0.0, 0.0};

  const int arow = w * 16 + lr;

  for (int kc = 0; kc < 24; kc++) {
#pragma unroll
    for (int it = 0; it < 2; it++) {
      const int idx = (it << 8) + tid;      // 0..511
      const int row = idx >> 3;             // 0..63
      const int kg  = idx & 7;              // float4 group within 32-k chunk
      const int gra = ti * 64 + row;
      const int ra  = (gra < N_) ? gra : (N_ - 1);
      const float4 va = *(const float4*)(X + (size_t)ra * D_ + kc * 32 + kg * 4);
      *(float4*)(As + row * 36 + kg * 4) = va;
      if (!diag) {
        const int grb = tj * 64 + row;
        const int rb  = (grb < N_) ? grb : (N_ - 1);
        const float4 vb = *(const float4*)(X + (size_t)rb * D_ + kc * 32 + kg * 4);
        *(float4*)(Bs + row * 36 + kg * 4) = vb;
      }
    }
    __syncthreads();
#pragma unroll
    for (int k4 = 0; k4 < 8; k4++) {
      const int kbase = k4 * 4 + lk;
      const double av  = (double)As[arow * 36 + kbase];
      const double bv0 = (double)Bsel[(lr     ) * 36 + kbase];
      const double bv1 = (double)Bsel[(16 + lr) * 36 + kbase];
      const double bv2 = (double)Bsel[(32 + lr) * 36 + kbase];
      const double bv3 = (double)Bsel[(48 + lr) * 36 + kbase];
      acc0 = __builtin_amdgcn_mfma_f64_16x16x4f64(av, bv0, acc0, 0, 0, 0);
      acc1 = __builtin_amdgcn_mfma_f64_16x16x4f64(av, bv1, acc1, 0, 0, 0);
      acc2 = __builtin_amdgcn_mfma_f64_16x16x4f64(av, bv2, acc2, 0, 0, 0);
      acc3 = __builtin_amdgcn_mfma_f64_16x16x4f64(av, bv3, acc3, 0, 0, 0);
    }
    __syncthreads();
  }

  // epilogue: scatter with probe-derived (i,j) — layout-agnostic
#pragma unroll
  for (int ct = 0; ct < 4; ct++) {
    const dbl4 a = (ct == 0) ? acc0 : (ct == 1) ? acc1 : (ct == 2) ? acc2 : acc3;
#pragma unroll
    for (int e = 0; e < 4; e++) {
      const int gi = ti * 64 + w * 16 + iofs[e];
      const int gj = tj * 64 + ct * 16 + jofs[e];
      if (gi < N_ && gj < N_) {
        Gp[(size_t)gi * GSTRIDE + gj] = a[e];
        if (!diag) Gp[(size_t)gj * GSTRIDE + gi] = a[e];
      }
    }
  }
}

// ---------------------------------------------------------------------------
// Kernel E2: sequential FPS using precomputed Gram, barrier-free. Wave 0
// owns all candidate slots (4/lane). gdc (diag of cand) comes from the
// owning lane's register via shfl instead of a dependent global load on the
// 48-step serial critical path.
// ---------------------------------------------------------------------------
__global__ __launch_bounds__(256) void kE2(const double* __restrict__ G,
                                           const float* __restrict__ mask,
                                           const int* __restrict__ fidxw,
                                           const float* __restrict__ x,
                                           float* __restrict__ out) {
  const int p = blockIdx.x;
  const int b = p >> 3;
  const int fi = fidxw[p];
  const double* Gp = G + (size_t)p * (GSTRIDE * GSTRIDE);
  const float* mrow = mask + (size_t)(b * T_ + fi) * N_;
  const float* X = x + ((size_t)(b * T_ + fi)) * (N_ * D_);
  const int tid = threadIdx.x;

  __shared__ int toksS[KT_];

  if (tid < 64) {
    const int l = tid;
    double gd[4]; int vld[4]; double md[4];
#pragma unroll
    for (int q = 0; q < 4; q++) {
      const int pt = l + 64 * q;
      const bool live = pt < N_;
      gd[q] = live ? Gp[(size_t)pt * GSTRIDE + pt] : 0.0;
      vld[q] = (live && (mrow[live ? pt : 0] > 0.5f)) ? 1 : 0;
      md[q] = -INFINITY;
    }

    // step 0: argmax over valid of diag (== argmax of where(valid,|X|^2,-inf))
    double bv = vld[0] ? gd[0] : -INFINITY;
    int bi = l;
#pragma unroll
    for (int q = 1; q < 4; q++) {
      const double v = vld[q] ? gd[q] : -INFINITY;
      if (v > bv) { bv = v; bi = l + 64 * q; }   // ascending pt: ties keep min
    }
#pragma unroll
    for (int off = 1; off < 64; off <<= 1) {
      const double ov = __shfl_xor(bv, off, 64);
      const int    oi = __shfl_xor(bi, off, 64);
      if (ov > bv || (ov == bv && oi < bi)) { bv = ov; bi = oi; }
    }
    int cand = bi;
    if (l == 0) toksS[0] = cand;

    for (int k = 1; k < KT_; k++) {
      const size_t rowbase = (size_t)cand * GSTRIDE;
      const double g0 = Gp[rowbase + l];
      const double g1 = Gp[rowbase + l + 64];
      const double g2 = Gp[rowbase + l + 128];
      // diag of cand from the owning lane's register (no dependent L2 load)
      const int cq = cand >> 6, cl = cand & 63;
      const double gsel = (cq == 0) ? gd[0] : (cq == 1) ? gd[1]
                        : (cq == 2) ? gd[2] : gd[3];
      const double gdc = __shfl(gsel, cl, 64);
      const double d0 = sqrt(fmax(gd[0] + gdc - 2.0 * g0, 0.0));
      const double d1 = sqrt(fmax(gd[1] + gdc - 2.0 * g1, 0.0));
      const double d2 = sqrt(fmax(gd[2] + gdc - 2.0 * g2, 0.0));
      md[0] = vld[0] ? ((k == 1) ? d0 : fmin(md[0], d0)) : -1.0;
      md[1] = vld[1] ? ((k == 1) ? d1 : fmin(md[1], d1)) : -1.0;
      md[2] = vld[2] ? ((k == 1) ? d2 : fmin(md[2], d2)) : -1.0;
      if (l + 192 < N_) {
        const double g3 = Gp[rowbase + l + 192];
        const double d3 = sqrt(fmax(gd[3] + gdc - 2.0 * g3, 0.0));
        md[3] = vld[3] ? ((k == 1) ? d3 : fmin(md[3], d3)) : -1.0;
      }

      bv = md[0]; bi = l;
      if (md[1] > bv) { bv = md[1]; bi = l + 64; }
      if (md[2] > bv) { bv = md[2]; bi = l + 128; }
      if (md[3] > bv) { bv = md[3]; bi = l + 192; }
#pragma unroll
      for (int off = 1; off < 64; off <<= 1) {
        const double ov = __shfl_xor(bv, off, 64);
        const int    oi = __shfl_xor(bi, off, 64);
        if (ov > bv || (ov == bv && oi < bi)) { bv = ov; bi = oi; }
      }
      cand = bi;
      if (l == 0) toksS[k] = cand;
    }
  }
  __syncthreads();

  // fused epilogue: token_idx, token_mask, z gather
  if (tid < KT_) {
    const int tok = toksS[tid];
    out[TI_OFF + p * KT_ + tid] = (float)tok;
    out[TM_OFF + (size_t)(b * T_ + fi) * N_ + tok] = 1.0f;
  }
  if (tid < 192) {
    for (int r = 0; r < KT_; r++) {
      const float4 v = *(const float4*)(X + (size_t)toksS[r] * D_ + tid * 4);
      *(float4*)(out + ((size_t)(p * KT_ + r)) * D_ + tid * 4) = v;
    }
  }
}

// ---------------------------------------------------------------------------
extern "C" void kernel_launch(void* const* d_in, const int* in_sizes, int n_in,
                              void* d_out, int out_size, void* d_ws, size_t ws_size,
                              hipStream_t stream) {
  (void)in_sizes; (void)n_in; (void)ws_size; (void)out_size;
  const float* x     = (const float*)d_in[0];
  const float* mask  = (const float*)d_in[1];
  const float* gamma = (const float*)d_in[2];
  const float* beta  = (const float*)d_in[3];
  const float* W1    = (const float*)d_in[4];
  const float* b1    = (const float*)d_in[5];
  const float* W2    = (const float*)d_in[6];
  const float* b2    = (const float*)d_in[7];
  float* out = (float*)d_out;
  char* ws = (char*)d_ws;

  double* scorep = (double*)(ws + WS_SCOREP);
  double* fn64   = (double*)(ws + WS_FN64);
  float*  h32    = (float*)(ws + WS_H32);
  int*    validw = (int*)(ws + WS_VALID);
  int*    fidxw  = (int*)(ws + WS_FIDX);
  double* simG   = (double*)(ws + WS_SIM);
  double* G      = (double*)(ws + WS_G);

  // zero only the token_mask region (everything else is fully overwritten)
  hipMemsetAsync(out + TM_OFF, 0, (size_t)TM_SZ * sizeof(float), stream);

  kA<<<B_ * T_, 256, 0, stream>>>(x, mask, gamma, beta, fn64, h32, validw);
  kSB<<<32 + (HIDD_ / 128) * ((B_ * T_) / 32), 256, 0, stream>>>(
      fn64, simG, h32, W1, b1, W2, scorep);
  kD<<<B_, 256, 0, stream>>>(simG, scorep, b2, fidxw, out + FI_OFF, out + FM_OFF);
  kG<<<B_ * KF_ * 10, 256, 0, stream>>>(x, fidxw, G);
  kE2<<<B_ * KF_, 256, 0, stream>>>(G, mask, fidxw, x, out);
}

// Round 5
// 701.266 us; speedup vs baseline: 1.0810x; 1.0075x over previous
//
#include <hip/hip_runtime.h>
#include <math.h>

// Problem constants
#define B_ 8
#define T_ 64
#define N_ 197
#define D_ 768
#define HIDD_ 3072   // HID*D
#define KF_ 8
#define KT_ 49
#define GSTRIDE 200  // padded row stride of per-pair Gram matrix (doubles)

typedef double dbl4 __attribute__((ext_vector_type(4)));

// Output layout (floats, concatenated in reference return order)
#define Z_SZ    (B_*KF_*KT_*D_)       // 2408448
#define FI_OFF  (Z_SZ)                // 2408448
#define TI_OFF  (FI_OFF + B_*KF_)     // 2408512
#define FM_OFF  (TI_OFF + B_*KF_*KT_) // 2411648
#define TM_OFF  (FM_OFF + B_*T_)      // 2412160
#define TM_SZ   (B_*T_*N_)            // 100864

// Workspace layout (bytes)
#define WS_SCOREP  0                          // 512*24 doubles = 98304
#define WS_FN64    98304                      // 512*768*8 = 3145728
#define WS_H32     (WS_FN64 + 3145728)        // 512*768*4 = 1572864
#define WS_VALID   (WS_H32 + 1572864)         // 512*4 = 2048
#define WS_FIDX    (WS_VALID + 2048)          // 64 ints (pad 256)
#define WS_SIM     (WS_FIDX + 256)            // 8*64*64*8 = 262144
#define WS_G       (WS_SIM + 262144)          // 64*200*200*8 = 20480000
// total ~25.6 MB

// ---------------------------------------------------------------------------
// Kernel A v2: masked-mean frame_repr (fp64), LayerNorm -> h32, L2-normalized
// fn64. One block per (b,t); all 256 threads own 3 dims (256*3 = 768) so all
// 4 waves issue loads. Per-dim masked sums keep exact per-accumulator order.
// ---------------------------------------------------------------------------
__global__ __launch_bounds__(256) void kA(const float* __restrict__ x,
                                          const float* __restrict__ mask,
                                          const float* __restrict__ gamma,
                                          const float* __restrict__ beta,
                                          double* __restrict__ fn64,
                                          float* __restrict__ h32,
                                          int* __restrict__ validw) {
  const int row = blockIdx.x;          // b*T + t
  const int tid = threadIdx.x;
  __shared__ float  ms[N_];
  __shared__ double red[256];
  __shared__ double sh_denom, sh_mu, sh_sd, sh_nrm;
  const float* xr = x + (size_t)row * (N_ * D_);

  if (tid < N_) ms[tid] = mask[(size_t)row * N_ + tid];
  __syncthreads();

  // denom = clip(sum(mask), 1e-6)  (same 197-entry tree as before)
  red[tid] = (tid < N_) ? (double)ms[tid] : 0.0;
  __syncthreads();
  for (int s = 128; s > 0; s >>= 1) { if (tid < s) red[tid] += red[tid + s]; __syncthreads(); }
  if (tid == 0) { double d = red[0]; sh_denom = (d > 1e-6) ? d : 1e-6; }
  __syncthreads();
  const double dn = sh_denom;

  // masked mean over n (fp64 accumulate); 3 consecutive floats per thread
  double a0 = 0.0, a1 = 0.0, a2 = 0.0;
  {
    const float* px = xr + tid * 3;
#pragma unroll 4
    for (int n = 0; n < N_; n++) {
      const double mv = (double)ms[n];
      const float* q = px + (size_t)n * D_;
      a0 += (double)q[0] * mv;
      a1 += (double)q[1] * mv;
      a2 += (double)q[2] * mv;
    }
  }
  const double f0 = a0 / dn, f1 = a1 / dn, f2 = a2 / dn;

  // mean
  red[tid] = f0 + f1 + f2; __syncthreads();
  for (int s = 128; s > 0; s >>= 1) { if (tid < s) red[tid] += red[tid + s]; __syncthreads(); }
  if (tid == 0) sh_mu = red[0] / (double)D_;
  __syncthreads();
  const double mu = sh_mu;

  // L2 norm (cosine normalize, eps 1e-12)
  red[tid] = f0 * f0 + f1 * f1 + f2 * f2; __syncthreads();
  for (int s = 128; s > 0; s >>= 1) { if (tid < s) red[tid] += red[tid + s]; __syncthreads(); }
  if (tid == 0) { double nr = sqrt(red[0]); sh_nrm = (nr > 1e-12) ? nr : 1e-12; }
  __syncthreads();

  // variance
  red[tid] = (f0 - mu) * (f0 - mu) + (f1 - mu) * (f1 - mu) + (f2 - mu) * (f2 - mu);
  __syncthreads();
  for (int s = 128; s > 0; s >>= 1) { if (tid < s) red[tid] += red[tid + s]; __syncthreads(); }
  if (tid == 0) sh_sd = sqrt(red[0] / (double)D_ + 1e-5);
  __syncthreads();
  const double sd = sh_sd, nrm = sh_nrm;

  {
    const size_t base = (size_t)row * D_ + tid * 3;
    const float g0 = gamma[tid * 3 + 0], g1 = gamma[tid * 3 + 1], g2 = gamma[tid * 3 + 2];
    const float e0 = beta[tid * 3 + 0],  e1 = beta[tid * 3 + 1],  e2 = beta[tid * 3 + 2];
    h32[base + 0] = (float)((f0 - mu) / sd * (double)g0 + (double)e0);
    h32[base + 1] = (float)((f1 - mu) / sd * (double)g1 + (double)e1);
    h32[base + 2] = (float)((f2 - mu) / sd * (double)g2 + (double)e2);
    fn64[base + 0] = f0 / nrm;
    fn64[base + 1] = f1 / nrm;
    fn64[base + 2] = f2 / nrm;
  }
  if (tid == 0) validw[row] = 1;  // clip(denom,1e-6) > 0 always
}

// ---------------------------------------------------------------------------
// Kernel SB: fused kS (sim = fn.fn^T, fp64, 32 blocks) and kB (score GEMM,
// 384 blocks). Independent producers for kD; one dispatch lets the small kS
// ride under kB. Shared-LDS union via char buffer.
// ---------------------------------------------------------------------------
__global__ __launch_bounds__(256) void kSB(const double* __restrict__ fn64,
                                           double* __restrict__ simG,
                                           const float* __restrict__ h32,
                                           const float* __restrict__ W1,
                                           const float* __restrict__ b1,
                                           const float* __restrict__ W2,
                                           double* __restrict__ scorep) {
  __shared__ char smem[42496] __attribute__((aligned(16)));
  const int tid = threadIdx.x;

  if (blockIdx.x < 32) {
    // ---- kS: parallel sim = fn.fn^T (fp64), same k-order as before ----
    const int b    = blockIdx.x >> 2;
    const int tile = blockIdx.x & 3;
    const int ty = tid >> 4;          // row within slab (0..15)
    const int tx = tid & 15;          // col group (0..15)
    double* As = (double*)smem;            // [kk][row16+pad] = 64*17 dbl
    double* Bs = (double*)(smem + 8704);   // [kk][col64+pad2] = 64*66 dbl
    double acc[4] = {0.0, 0.0, 0.0, 0.0};

    for (int kc = 0; kc < 12; kc++) {
#pragma unroll
      for (int it = 0; it < 4; it++) {          // A slab: 16x64 dbl
        const int idx = (it << 8) + tid;
        const int row = idx >> 6, kk = idx & 63;
        As[kk * 17 + row] = fn64[((size_t)(b * T_ + tile * 16 + row)) * D_ + kc * 64 + kk];
      }
#pragma unroll
      for (int it = 0; it < 16; it++) {         // B slab: 64x64 dbl
        const int idx = (it << 8) + tid;
        const int row = idx >> 6, kk = idx & 63;
        Bs[kk * 66 + row] = fn64[((size_t)(b * T_ + row)) * D_ + kc * 64 + kk];
      }
      __syncthreads();
#pragma unroll 8
      for (int kk = 0; kk < 64; kk++) {
        const double a = As[kk * 17 + ty];
        const double* bp = Bs + kk * 66 + tx * 4;
        acc[0] += a * bp[0];
        acc[1] += a * bp[1];
        acc[2] += a * bp[2];
        acc[3] += a * bp[3];
      }
      __syncthreads();
    }
    double* o = simG + ((size_t)b * 64 + tile * 16 + ty) * 64 + tx * 4;
    o[0] = acc[0]; o[1] = acc[1]; o[2] = acc[2]; o[3] = acc[3];
  } else {
    // ---- kB: score partials = gelu(h @ W1 + b1) @ W2 per n-block ----
    const int bid2 = blockIdx.x - 32;
    const int nb = bid2 % 24;          // n-block (0..23)
    const int n0 = nb * 128;
    const int m0 = (bid2 / 24) * 32;
    const int tx = tid & 31;   // 32 col-groups of 4
    const int ty = tid >> 5;   // 8 row-groups of 4
    float* As = (float*)smem;            // [k][m], pad 36 -> b128-aligned
    float* Bs = (float*)(smem + 9216);   // [k][n] = 64*128 f32
    float acc[4][4];
#pragma unroll
    for (int r = 0; r < 4; r++)
#pragma unroll
      for (int c = 0; c < 4; c++) acc[r][c] = 0.0f;

    for (int kc = 0; kc < 12; kc++) {
      const int k0 = kc * 64;
#pragma unroll
      for (int it = 0; it < 8; it++) {           // A: 32x64
        int idx = tid + (it << 8);
        int k = idx & 63, m = idx >> 6;
        As[k * 36 + m] = h32[(size_t)(m0 + m) * D_ + k0 + k];
      }
#pragma unroll
      for (int it = 0; it < 8; it++) {           // B: 64x128 float4
        int idx = tid + (it << 8);
        int k = idx >> 5, n4 = idx & 31;
        const float4 v = *(const float4*)(W1 + (size_t)(k0 + k) * HIDD_ + n0 + (n4 << 2));
        *(float4*)(Bs + k * 128 + (n4 << 2)) = v;
      }
      __syncthreads();
#pragma unroll 16
      for (int kk = 0; kk < 64; kk++) {
        float4 av = *(const float4*)(As + kk * 36 + ty * 4);
        float4 bv = *(const float4*)(Bs + kk * 128 + tx * 4);
        const float a[4] = {av.x, av.y, av.z, av.w};
        const float bb[4] = {bv.x, bv.y, bv.z, bv.w};
#pragma unroll
        for (int r = 0; r < 4; r++)
#pragma unroll
          for (int c = 0; c < 4; c++) acc[r][c] += a[r] * bb[c];
      }
      __syncthreads();
    }

    double part[4] = {0.0, 0.0, 0.0, 0.0};
#pragma unroll
    for (int r = 0; r < 4; r++) {
#pragma unroll
      for (int c = 0; c < 4; c++) {
        const int gn = n0 + tx * 4 + c;
        const double v = (double)(acc[r][c] + b1[gn]);
        const double g = 0.5 * v * (1.0 + erf(v * 0.7071067811865475244));
        part[r] += g * (double)W2[gn];
      }
    }
#pragma unroll
    for (int r = 0; r < 4; r++) {
      double s = part[r];
#pragma unroll
      for (int off = 16; off > 0; off >>= 1) s += __shfl_down(s, off, 32);
      if (tx == 0) scorep[(size_t)(m0 + ty * 4 + r) * 24 + nb] = s;
    }
  }
}

// ---------------------------------------------------------------------------
// Kernel D: facility-location greedy, barrier-free wave-synchronous (wave 0
// runs 8 steps with shfl-only state after a single LDS sim load/barrier).
// ---------------------------------------------------------------------------
__global__ __launch_bounds__(256) void kD(const double* __restrict__ simG,
                                          const double* __restrict__ scorep,
                                          const float* __restrict__ b2,
                                          int* __restrict__ fidxw,
                                          float* __restrict__ out_fidx,
                                          float* __restrict__ out_fmask) {
  const int b = blockIdx.x;
  const int tid = threadIdx.x;
  __shared__ double sim[64 * 64];

  const double2* sp = (const double2*)(simG + (size_t)b * 4096);
#pragma unroll
  for (int it = 0; it < 8; it++) {
    const int idx = (it << 8) + tid;
    ((double2*)sim)[idx] = sp[idx];
  }
  __syncthreads();

  if (tid < 64) {
    // per-lane score (same 24-term summation order as before)
    double s = 0.0;
    const double* pp = scorep + (size_t)(b * T_ + tid) * 24;
    for (int q = 0; q < 24; q++) s += pp[q];
    const double half_score = 0.5 * (s + (double)b2[0]);  // valid always true

    double bc_r = 0.0;
    int chosen_r = 0;

    for (int step = 0; step < KF_; step++) {
      // coverage gain for candidate tid (same ascending-ii fp64 add order)
      double gsum = 0.0;
      for (int ii = 0; ii < 64; ii++) {
        const double bcv = __shfl(bc_r, ii, 64);
        gsum += fmax(bcv, sim[ii * 64 + tid]);
      }
      double tot = gsum + half_score;
      if (chosen_r) tot = -INFINITY;

      // wave argmax, first-max (min index) tie-break == jnp.argmax
      double bv = tot; int bi = tid;
#pragma unroll
      for (int off = 1; off < 64; off <<= 1) {
        const double ov = __shfl_xor(bv, off, 64);
        const int    oi = __shfl_xor(bi, off, 64);
        if (ov > bv || (ov == bv && oi < bi)) { bv = ov; bi = oi; }
      }
      bc_r = fmax(bc_r, sim[bi * 64 + tid]);   // symmetric: == sim[tid][bi]
      if (tid == bi) chosen_r = 1;
      if (tid == 0) {
        fidxw[b * KF_ + step] = bi;
        out_fidx[b * KF_ + step] = (float)bi;
      }
    }
    out_fmask[b * T_ + tid] = chosen_r ? 1.0f : 0.0f;
  }
}

// ---------------------------------------------------------------------------
// Kernel G v5: per-pair Gram via v_mfma_f64_16x16x4_f64, self-calibrated D
// layout (v4), now with padding-aware tiling. Row-block 3 holds only 5 real
// rows (192-196); v4 spent 4 full 64x64 tiles on it. v5: 6 full tiles
// (i<=j<3) + ONE combo block whose wave w computes the 16-row strip of tile
// (3,w) (w<3: 16x64; w=3: the 16x16 diagonal corner). Per-pair dots
// 40960 -> 27904 (-32% mfma work). Per-output k-contraction order unchanged
// -> surviving G entries bit-identical to v4. Grid 64 pairs x 7 = 448,
// XCD-aligned (pair's 7 blocks share bid&7 -> one XCD L2).
// ---------------------------------------------------------------------------
__global__ __launch_bounds__(256) void kG(const float* __restrict__ x,
                                          const int* __restrict__ fidxw,
                                          double* __restrict__ G) {
  static const int TIa[6] = {0,0,0,1,1,2};
  static const int TJa[6] = {0,1,2,1,2,2};
  const int bid  = blockIdx.x;
  const int xcd  = bid & 7;
  const int slot = bid >> 3;            // 0..55
  const int p    = xcd + 8 * (slot / 7);
  const int t    = slot % 7;            // 0..5 full tiles, 6 = combo
  const int b  = p >> 3;
  const int fi = fidxw[p];
  const float* X = x + ((size_t)(b * T_ + fi)) * (N_ * D_);
  double* Gp = G + (size_t)p * (GSTRIDE * GSTRIDE);

  // shared buffer: full tiles use 2x 64x36; combo uses 208x36 (A16 + B192)
  __shared__ float buf[208 * 36];
  const int tid  = threadIdx.x;
  const int w    = tid >> 6;      // wave id
  const int lane = tid & 63;
  const int lr   = lane & 15;     // A row-in-strip / B col-in-tile
  const int lk   = lane >> 4;     // k slot 0..3

  // ---- D-layout probe (exact small-int arithmetic) ----
  dbl4 pz = {0.0, 0.0, 0.0, 0.0};
  const dbl4 p1 = __builtin_amdgcn_mfma_f64_16x16x4f64((double)lr, 1.0, pz, 0, 0, 0);
  const dbl4 p2 = __builtin_amdgcn_mfma_f64_16x16x4f64(1.0, (double)lr, pz, 0, 0, 0);
  int iofs[4], jofs[4];
#pragma unroll
  for (int e = 0; e < 4; e++) {
    iofs[e] = (int)(p1[e] * 0.25 + 0.5);   // true row of (lane, reg e)
    jofs[e] = (int)(p2[e] * 0.25 + 0.5);   // true col of (lane, reg e)
  }

  dbl4 acc0 = {0.0, 0.0, 0.0, 0.0};
  dbl4 acc1 = {0.0, 0.0, 0.0, 0.0};
  dbl4 acc2 = {0.0, 0.0, 0.0, 0.0};
  dbl4 acc3 = {0.0, 0.0, 0.0, 0.0};

  if (t < 6) {
    // ================= full 64x64 tile =================
    const int ti = TIa[t], tj = TJa[t];
    const bool diag = (ti == tj);
    float* As = buf;                 // [row64][k32+pad4]
    float* Bs = buf + 64 * 36;
    const float* Bsel = diag ? As : Bs;
    const int arow = w * 16 + lr;

    for (int kc = 0; kc < 24; kc++) {
#pragma unroll
      for (int it = 0; it < 2; it++) {
        const int idx = (it << 8) + tid;      // 0..511
        const int row = idx >> 3;             // 0..63
        const int kg  = idx & 7;
        const int gra = ti * 64 + row;
        const int ra  = (gra < N_) ? gra : (N_ - 1);
        const float4 va = *(const float4*)(X + (size_t)ra * D_ + kc * 32 + kg * 4);
        *(float4*)(As + row * 36 + kg * 4) = va;
        if (!diag) {
          const int grb = tj * 64 + row;
          const int rb  = (grb < N_) ? grb : (N_ - 1);
          const float4 vb = *(const float4*)(X + (size_t)rb * D_ + kc * 32 + kg * 4);
          *(float4*)(Bs + row * 36 + kg * 4) = vb;
        }
      }
      __syncthreads();
#pragma unroll
      for (int k4 = 0; k4 < 8; k4++) {
        const int kbase = k4 * 4 + lk;
        const double av  = (double)As[arow * 36 + kbase];
        const double bv0 = (double)Bsel[(lr     ) * 36 + kbase];
        const double bv1 = (double)Bsel[(16 + lr) * 36 + kbase];
        const double bv2 = (double)Bsel[(32 + lr) * 36 + kbase];
        const double bv3 = (double)Bsel[(48 + lr) * 36 + kbase];
        acc0 = __builtin_amdgcn_mfma_f64_16x16x4f64(av, bv0, acc0, 0, 0, 0);
        acc1 = __builtin_amdgcn_mfma_f64_16x16x4f64(av, bv1, acc1, 0, 0, 0);
        acc2 = __builtin_amdgcn_mfma_f64_16x16x4f64(av, bv2, acc2, 0, 0, 0);
        acc3 = __builtin_amdgcn_mfma_f64_16x16x4f64(av, bv3, acc3, 0, 0, 0);
      }
      __syncthreads();
    }

#pragma unroll
    for (int ct = 0; ct < 4; ct++) {
      const dbl4 a = (ct == 0) ? acc0 : (ct == 1) ? acc1 : (ct == 2) ? acc2 : acc3;
#pragma unroll
      for (int e = 0; e < 4; e++) {
        const int gi = ti * 64 + w * 16 + iofs[e];
        const int gj = tj * 64 + ct * 16 + jofs[e];
        // ti,tj < 3 -> gi,gj < 192 < N_ always
        Gp[(size_t)gi * GSTRIDE + gj] = a[e];
        if (!diag) Gp[(size_t)gj * GSTRIDE + gi] = a[e];
      }
    }
  } else {
    // ================= combo block: row-block 3 strips =================
    // LDS: rows 0..15  = A-slab (global rows 192..207, clamped)
    //      rows 16..207 = B rows 0..191 (global row = r-16)
    for (int kc = 0; kc < 24; kc++) {
#pragma unroll
      for (int it = 0; it < 7; it++) {
        const int idx = (it << 8) + tid;      // 0..1791, need 0..1663
        if (idx < 208 * 8) {
          const int r  = idx >> 3;            // 0..207
          const int kg = idx & 7;
          int grow;
          if (r < 16) { const int g = 192 + r; grow = (g < N_) ? g : (N_ - 1); }
          else        { grow = r - 16; }
          const float4 v = *(const float4*)(X + (size_t)grow * D_ + kc * 32 + kg * 4);
          *(float4*)(buf + r * 36 + kg * 4) = v;
        }
      }
      __syncthreads();
#pragma unroll
      for (int k4 = 0; k4 < 8; k4++) {
        const int kbase = k4 * 4 + lk;
        const double av = (double)buf[lr * 36 + kbase];   // A-slab row lr
        if (w < 3) {
          const int bbase = 16 + w * 64;
          const double bv0 = (double)buf[(bbase      + lr) * 36 + kbase];
          const double bv1 = (double)buf[(bbase + 16 + lr) * 36 + kbase];
          const double bv2 = (double)buf[(bbase + 32 + lr) * 36 + kbase];
          const double bv3 = (double)buf[(bbase + 48 + lr) * 36 + kbase];
          acc0 = __builtin_amdgcn_mfma_f64_16x16x4f64(av, bv0, acc0, 0, 0, 0);
          acc1 = __builtin_amdgcn_mfma_f64_16x16x4f64(av, bv1, acc1, 0, 0, 0);
          acc2 = __builtin_amdgcn_mfma_f64_16x16x4f64(av, bv2, acc2, 0, 0, 0);
          acc3 = __builtin_amdgcn_mfma_f64_16x16x4f64(av, bv3, acc3, 0, 0, 0);
        } else {
          // diagonal corner (3,3): B col j = global row 192+j = A-slab row j
          acc0 = __builtin_amdgcn_mfma_f64_16x16x4f64(av, av, acc0, 0, 0, 0);
        }
      }
      __syncthreads();
    }

    if (w < 3) {
#pragma unroll
      for (int ct = 0; ct < 4; ct++) {
        const dbl4 a = (ct == 0) ? acc0 : (ct == 1) ? acc1 : (ct == 2) ? acc2 : acc3;
#pragma unroll
        for (int e = 0; e < 4; e++) {
          const int gi = 192 + iofs[e];            // row in block 3
          const int gj = w * 64 + ct * 16 + jofs[e];  // col < 192 always
          if (gi < N_) {
            Gp[(size_t)gi * GSTRIDE + gj] = a[e];
            Gp[(size_t)gj * GSTRIDE + gi] = a[e];  // mirror (always off-diag)
          }
        }
      }
    } else {
#pragma unroll
      for (int e = 0; e < 4; e++) {
        const int gi = 192 + iofs[e];
        const int gj = 192 + jofs[e];
        if (gi < N_ && gj < N_) Gp[(size_t)gi * GSTRIDE + gj] = acc0[e];
        // full 16x16 covers both triangles; no mirror needed
      }
    }
  }
}

// ---------------------------------------------------------------------------
// Kernel E2: sequential FPS using precomputed Gram, barrier-free. Wave 0
// owns all candidate slots (4/lane). gdc (diag of cand) comes from the
// owning lane's register via shfl instead of a dependent global load on the
// 48-step serial critical path.
// ---------------------------------------------------------------------------
__global__ __launch_bounds__(256) void kE2(const double* __restrict__ G,
                                           const float* __restrict__ mask,
                                           const int* __restrict__ fidxw,
                                           const float* __restrict__ x,
                                           float* __restrict__ out) {
  const int p = blockIdx.x;
  const int b = p >> 3;
  const int fi = fidxw[p];
  const double* Gp = G + (size_t)p * (GSTRIDE * GSTRIDE);
  const float* mrow = mask + (size_t)(b * T_ + fi) * N_;
  const float* X = x + ((size_t)(b * T_ + fi)) * (N_ * D_);
  const int tid = threadIdx.x;

  __shared__ int toksS[KT_];

  if (tid < 64) {
    const int l = tid;
    double gd[4]; int vld[4]; double md[4];
#pragma unroll
    for (int q = 0; q < 4; q++) {
      const int pt = l + 64 * q;
      const bool live = pt < N_;
      gd[q] = live ? Gp[(size_t)pt * GSTRIDE + pt] : 0.0;
      vld[q] = (live && (mrow[live ? pt : 0] > 0.5f)) ? 1 : 0;
      md[q] = -INFINITY;
    }

    // step 0: argmax over valid of diag (== argmax of where(valid,|X|^2,-inf))
    double bv = vld[0] ? gd[0] : -INFINITY;
    int bi = l;
#pragma unroll
    for (int q = 1; q < 4; q++) {
      const double v = vld[q] ? gd[q] : -INFINITY;
      if (v > bv) { bv = v; bi = l + 64 * q; }   // ascending pt: ties keep min
    }
#pragma unroll
    for (int off = 1; off < 64; off <<= 1) {
      const double ov = __shfl_xor(bv, off, 64);
      const int    oi = __shfl_xor(bi, off, 64);
      if (ov > bv || (ov == bv && oi < bi)) { bv = ov; bi = oi; }
    }
    int cand = bi;
    if (l == 0) toksS[0] = cand;

    for (int k = 1; k < KT_; k++) {
      const size_t rowbase = (size_t)cand * GSTRIDE;
      const double g0 = Gp[rowbase + l];
      const double g1 = Gp[rowbase + l + 64];
      const double g2 = Gp[rowbase + l + 128];
      // diag of cand from the owning lane's register (no dependent L2 load)
      const int cq = cand >> 6, cl = cand & 63;
      const double gsel = (cq == 0) ? gd[0] : (cq == 1) ? gd[1]
                        : (cq == 2) ? gd[2] : gd[3];
      const double gdc = __shfl(gsel, cl, 64);
      const double d0 = sqrt(fmax(gd[0] + gdc - 2.0 * g0, 0.0));
      const double d1 = sqrt(fmax(gd[1] + gdc - 2.0 * g1, 0.0));
      const double d2 = sqrt(fmax(gd[2] + gdc - 2.0 * g2, 0.0));
      md[0] = vld[0] ? ((k == 1) ? d0 : fmin(md[0], d0)) : -1.0;
      md[1] = vld[1] ? ((k == 1) ? d1 : fmin(md[1], d1)) : -1.0;
      md[2] = vld[2] ? ((k == 1) ? d2 : fmin(md[2], d2)) : -1.0;
      if (l + 192 < N_) {
        const double g3 = Gp[rowbase + l + 192];
        const double d3 = sqrt(fmax(gd[3] + gdc - 2.0 * g3, 0.0));
        md[3] = vld[3] ? ((k == 1) ? d3 : fmin(md[3], d3)) : -1.0;
      }

      bv = md[0]; bi = l;
      if (md[1] > bv) { bv = md[1]; bi = l + 64; }
      if (md[2] > bv) { bv = md[2]; bi = l + 128; }
      if (md[3] > bv) { bv = md[3]; bi = l + 192; }
#pragma unroll
      for (int off = 1; off < 64; off <<= 1) {
        const double ov = __shfl_xor(bv, off, 64);
        const int    oi = __shfl_xor(bi, off, 64);
        if (ov > bv || (ov == bv && oi < bi)) { bv = ov; bi = oi; }
      }
      cand = bi;
      if (l == 0) toksS[k] = cand;
    }
  }
  __syncthreads();

  // fused epilogue: token_idx, token_mask, z gather
  if (tid < KT_) {
    const int tok = toksS[tid];
    out[TI_OFF + p * KT_ + tid] = (float)tok;
    out[TM_OFF + (size_t)(b * T_ + fi) * N_ + tok] = 1.0f;
  }
  if (tid < 192) {
    for (int r = 0; r < KT_; r++) {
      const float4 v = *(const float4*)(X + (size_t)toksS[r] * D_ + tid * 4);
      *(float4*)(out + ((size_t)(p * KT_ + r)) * D_ + tid * 4) = v;
    }
  }
}

// ---------------------------------------------------------------------------
extern "C" void kernel_launch(void* const* d_in, const int* in_sizes, int n_in,
                              void* d_out, int out_size, void* d_ws, size_t ws_size,
                              hipStream_t stream) {
  (void)in_sizes; (void)n_in; (void)ws_size; (void)out_size;
  const float* x     = (const float*)d_in[0];
  const float* mask  = (const float*)d_in[1];
  const float* gamma = (const float*)d_in[2];
  const float* beta  = (const float*)d_in[3];
  const float* W1    = (const float*)d_in[4];
  const float* b1    = (const float*)d_in[5];
  const float* W2    = (const float*)d_in[6];
  const float* b2    = (const float*)d_in[7];
  float* out = (float*)d_out;
  char* ws = (char*)d_ws;

  double* scorep = (double*)(ws + WS_SCOREP);
  double* fn64   = (double*)(ws + WS_FN64);
  float*  h32    = (float*)(ws + WS_H32);
  int*    validw = (int*)(ws + WS_VALID);
  int*    fidxw  = (int*)(ws + WS_FIDX);
  double* simG   = (double*)(ws + WS_SIM);
  double* G      = (double*)(ws + WS_G);

  // zero only the token_mask region (everything else is fully overwritten)
  hipMemsetAsync(out + TM_OFF, 0, (size_t)TM_SZ * sizeof(float), stream);

  kA<<<B_ * T_, 256, 0, stream>>>(x, mask, gamma, beta, fn64, h32, validw);
  kSB<<<32 + (HIDD_ / 128) * ((B_ * T_) / 32), 256, 0, stream>>>(
      fn64, simG, h32, W1, b1, W2, scorep);
  kD<<<B_, 256, 0, stream>>>(simG, scorep, b2, fidxw, out + FI_OFF, out + FM_OFF);
  kG<<<B_ * KF_ * 7, 256, 0, stream>>>(x, fidxw, G);
  kE2<<<B_ * KF_, 256, 0, stream>>>(G, mask, fidxw, x, out);
}